// Round 3
// baseline (231.705 us; speedup 1.0000x reference)
//
#include <hip/hip_runtime.h>

// Problem constants
#define DIMV   512
#define NEMB   4096
#define NTOK   32768                 // B*H*W
#define TOTAL  (NTOK * DIMV)        // 16,777,216

// Output layout (flat f32, concatenated in return order)
#define OFF_Q    0u
#define OFF_DIFF 16777216u
#define OFF_IND  16777217u
#define OFF_NE   16809985u
#define OFF_NCS  18907137u
#define OFF_NEA  18911233u

// ws layout (float-element offsets)
#define WS_SUMT    0u          // float [NEMB][DIMV]  (8 MB)
#define WS_BINCNT  2097152u    // int[4096]
#define WS_BINST   2101248u    // int[4096]
#define WS_SORTED  2105344u    // int[32768]
#define WS_DIFF    2138112u    // float
#define WS_NSUM    2138113u    // float

#define DECAYF 0.99f
#define OMDF   0.01f
#define EPSF   1e-5f

// ---------------------------------------------------------------------------
// Single-block fused sort: histogram + embed_ind + ncs + n_sum + scan +
// counting-sort scatter. Also zeroes diff_acc (replaces memset node).
__global__ __launch_bounds__(1024) void k_sort(
        const int*   __restrict__ labels,
        const float* __restrict__ cluster_size,
        float* __restrict__ out,
        int*   __restrict__ bin_count,
        int*   __restrict__ bin_start,
        int*   __restrict__ sorted_tok,
        float* __restrict__ n_sum,
        float* __restrict__ diff_acc) {
    __shared__ int   hist[NEMB];    // 16 KB; becomes cursor after scan
    __shared__ int   part[1024];    // 4 KB scan temp
    __shared__ float fred[1024];    // 4 KB ncs-sum reduce
    int t = threadIdx.x;
    #pragma unroll
    for (int i = 0; i < 4; ++i) hist[t + i * 1024] = 0;
    __syncthreads();

    // histogram + embed_ind (int4 loads; labels cached in registers)
    int4 labs[8];
    #pragma unroll
    for (int i = 0; i < 8; ++i) {
        int n4 = (i * 1024 + t) * 4;
        int4 l = *(const int4*)(labels + n4);
        labs[i] = l;
        out[OFF_IND + n4 + 0] = (float)l.x;
        out[OFF_IND + n4 + 1] = (float)l.y;
        out[OFF_IND + n4 + 2] = (float)l.z;
        out[OFF_IND + n4 + 3] = (float)l.w;
        atomicAdd(&hist[l.x], 1); atomicAdd(&hist[l.y], 1);
        atomicAdd(&hist[l.z], 1); atomicAdd(&hist[l.w], 1);
    }
    __syncthreads();

    // counts -> global, ncs, thread-local exclusive prefix
    int c[4]; int csum = 0; float nl = 0.f;
    #pragma unroll
    for (int i = 0; i < 4; ++i) {
        int b = t * 4 + i;
        int cc = hist[b];
        c[i] = csum; csum += cc;
        bin_count[b] = cc;
        float ncs = cluster_size[b] * DECAYF + OMDF * (float)cc;
        out[OFF_NCS + b] = ncs;
        nl += ncs;
    }
    part[t] = csum;
    fred[t] = nl;
    __syncthreads();
    // Hillis-Steele inclusive scan over 1024 thread-totals
    for (int o = 1; o < 1024; o <<= 1) {
        int v = (t >= o) ? part[t - o] : 0;
        __syncthreads();
        part[t] += v;
        __syncthreads();
    }
    // reduce ncs sum -> n_sum
    for (int o = 512; o > 0; o >>= 1) {
        if (t < o) fred[t] += fred[t + o];
        __syncthreads();
    }
    if (t == 0) { n_sum[0] = fred[0]; diff_acc[0] = 0.f; }

    int base = part[t] - csum;       // exclusive block offset
    int bs[4];
    #pragma unroll
    for (int i = 0; i < 4; ++i) {
        bs[i] = base + c[i];
        bin_start[t * 4 + i] = bs[i];
    }
    __syncthreads();
    #pragma unroll
    for (int i = 0; i < 4; ++i) hist[t * 4 + i] = bs[i];   // cursor
    __syncthreads();

    // scatter
    #pragma unroll
    for (int i = 0; i < 8; ++i) {
        int n4 = (i * 1024 + t) * 4;
        int4 l = labs[i];
        sorted_tok[atomicAdd(&hist[l.x], 1)] = n4 + 0;
        sorted_tok[atomicAdd(&hist[l.y], 1)] = n4 + 1;
        sorted_tok[atomicAdd(&hist[l.z], 1)] = n4 + 2;
        sorted_tok[atomicAdd(&hist[l.w], 1)] = n4 + 3;
    }
}

// ---------------------------------------------------------------------------
// One block per codebook entry: fused quantize + diff + segment sum.
// 4 waves; wave w handles tokens i = w, w+4, ... (no intra-loop syncs).
// Lane owns 8 dims (two float4s) -> 32 B/thread per token in flight.
#define CHUNK 128
__global__ __launch_bounds__(256) void k_perlabel(
        const float* __restrict__ inp,
        const float* __restrict__ embed,
        const int*   __restrict__ sorted_tok,
        const int*   __restrict__ bin_start,
        const int*   __restrict__ bin_count,
        float* __restrict__ out,
        float* __restrict__ sumT,
        float* __restrict__ diff_acc) {
    int e    = blockIdx.x;
    int t    = threadIdx.x;
    int wave = t >> 6;
    int lane = t & 63;
    int d0   = lane << 3;            // 8 dims per lane

    // embed column e (scattered scalar loads, once per block; L2-shared)
    float qa0 = embed[(size_t)(d0 + 0) * NEMB + e];
    float qa1 = embed[(size_t)(d0 + 1) * NEMB + e];
    float qa2 = embed[(size_t)(d0 + 2) * NEMB + e];
    float qa3 = embed[(size_t)(d0 + 3) * NEMB + e];
    float qb0 = embed[(size_t)(d0 + 4) * NEMB + e];
    float qb1 = embed[(size_t)(d0 + 5) * NEMB + e];
    float qb2 = embed[(size_t)(d0 + 6) * NEMB + e];
    float qb3 = embed[(size_t)(d0 + 7) * NEMB + e];
    float4 qa = make_float4(qa0, qa1, qa2, qa3);
    float4 qb = make_float4(qb0, qb1, qb2, qb3);

    int start = bin_start[e];
    int cnt   = bin_count[e];

    __shared__ int toks[CHUNK];
    float4 sa = make_float4(0, 0, 0, 0);
    float4 sb = make_float4(0, 0, 0, 0);
    float dacc = 0.f;

    for (int base = 0; base < cnt; base += CHUNK) {
        int m = min(CHUNK, cnt - base);
        if (t < m) toks[t] = sorted_tok[start + base + t];
        __syncthreads();
        #pragma unroll 2
        for (int i = wave; i < m; i += 4) {
            int n = toks[i];
            const float* row = inp + (size_t)n * DIMV + d0;
            float4 xa = *(const float4*)(row);
            float4 xb = *(const float4*)(row + 4);
            sa.x += xa.x; sa.y += xa.y; sa.z += xa.z; sa.w += xa.w;
            sb.x += xb.x; sb.y += xb.y; sb.z += xb.z; sb.w += xb.w;
            float t0 = qa.x - xa.x, t1 = qa.y - xa.y, t2 = qa.z - xa.z, t3 = qa.w - xa.w;
            float u0 = qb.x - xb.x, u1 = qb.y - xb.y, u2 = qb.z - xb.z, u3 = qb.w - xb.w;
            dacc += t0 * t0 + t1 * t1 + t2 * t2 + t3 * t3
                  + u0 * u0 + u1 * u1 + u2 * u2 + u3 * u3;
            float* orow = out + OFF_Q + (size_t)n * DIMV + d0;
            *(float4*)(orow)     = qa;
            *(float4*)(orow + 4) = qb;
        }
        __syncthreads();
    }

    // merge 4 wave partial sums -> sumT[e][*]
    __shared__ float ssum[4][DIMV];  // 8 KB
    *(float4*)(&ssum[wave][d0])     = sa;
    *(float4*)(&ssum[wave][d0 + 4]) = sb;
    __syncthreads();
    for (int d = t; d < DIMV; d += 256) {
        sumT[(size_t)e * DIMV + d] =
            ssum[0][d] + ssum[1][d] + ssum[2][d] + ssum[3][d];
    }
    // diff block reduce -> one atomic
    __shared__ float sh[256];
    sh[t] = dacc;
    __syncthreads();
    for (int o = 128; o > 0; o >>= 1) {
        if (t < o) sh[t] += sh[t + o];
        __syncthreads();
    }
    if (t == 0) atomicAdd(diff_acc, sh[0]);
}

// ---------------------------------------------------------------------------
// Tiled transpose of sumT [e][d] + EMA + normalize + diff finalize.
__global__ __launch_bounds__(256) void k_trans_final(
        const float* __restrict__ embed_avg,
        const float* __restrict__ sumT,
        const float* __restrict__ n_sum,
        const float* __restrict__ diff_acc,
        float* __restrict__ out) {
    __shared__ float tile[32][33];
    int tx = threadIdx.x & 31;
    int ty = threadIdx.x >> 5;
    int e0 = (blockIdx.x & 127) << 5;
    int d0 = (blockIdx.x >> 7) << 5;
    for (int i = 0; i < 4; ++i) {
        int er = ty + i * 8;
        tile[er][tx] = sumT[(size_t)(e0 + er) * DIMV + d0 + tx];
    }
    __syncthreads();
    float nsum = n_sum[0];
    float ncs  = out[OFF_NCS + e0 + tx];
    float cs   = (ncs + EPSF) / (nsum + (float)NEMB * EPSF) * nsum;
    float inv  = 1.0f / cs;
    for (int i = 0; i < 4; ++i) {
        int dr = d0 + ty + i * 8;
        size_t o = (size_t)dr * NEMB + e0 + tx;
        float val = DECAYF * embed_avg[o] + OMDF * tile[tx][ty + i * 8];
        out[OFF_NEA + o] = val;
        out[OFF_NE + o]  = val * inv;
    }
    if (blockIdx.x == 0 && threadIdx.x == 0)
        out[OFF_DIFF] = diff_acc[0] * (1.0f / (float)TOTAL);
}

// ---------------------------------------------------------------------------
extern "C" void kernel_launch(void* const* d_in, const int* in_sizes, int n_in,
                              void* d_out, int out_size, void* d_ws, size_t ws_size,
                              hipStream_t stream) {
    const float* inp          = (const float*)d_in[0];
    const int*   labels       = (const int*)  d_in[1];
    const float* embed        = (const float*)d_in[2];
    const float* cluster_size = (const float*)d_in[3];
    const float* embed_avg    = (const float*)d_in[4];
    float* out = (float*)d_out;

    float* wsf        = (float*)d_ws;
    float* sumT       = wsf + WS_SUMT;
    int*   bin_count  = (int*)(wsf + WS_BINCNT);
    int*   bin_start  = (int*)(wsf + WS_BINST);
    int*   sorted_tok = (int*)(wsf + WS_SORTED);
    float* diff_acc   = wsf + WS_DIFF;
    float* n_sum      = wsf + WS_NSUM;

    k_sort      <<<1,    1024, 0, stream>>>(labels, cluster_size, out,
                                            bin_count, bin_start, sorted_tok,
                                            n_sum, diff_acc);
    k_perlabel  <<<4096, 256,  0, stream>>>(inp, embed, sorted_tok, bin_start,
                                            bin_count, out, sumT, diff_acc);
    k_trans_final<<<2048,256,  0, stream>>>(embed_avg, sumT, n_sum, diff_acc, out);
}